// Round 4
// baseline (2882.165 us; speedup 1.0000x reference)
//
#include <hip/hip_runtime.h>
#include <math.h>

#define Bn 4096
#define Cn 50
#define En 128
#define Mn 200000
#define Fn 512
#define CAPA 4096
#define CAPB 2048
#define NBUCK 3136       // ceil(200000/64) = 3125, padded
#define NB_SIMM 784
#define NB_MC 512
#define NB_PS 64
#define NB_KH 256
#define HBINS 4096
#define DKd 11.313708498984761
#define DKf 11.313708498984761f

__device__ __forceinline__ unsigned sortkey(float f){
  unsigned u = __float_as_uint(f);
  return (u & 0x80000000u) ? ~u : (u | 0x80000000u);
}

__device__ __forceinline__ double log_sig(double x){
  return (x >= 0.0) ? -log1p(exp(-x)) : (x - log1p(exp(x)));
}

__device__ __forceinline__ double shfl_down_d(double x, int off){
  int lo = __shfl_down(__double2loint(x), off, 64);
  int hi = __shfl_down(__double2hiint(x), off, 64);
  return __hiloint2double(hi, lo);
}

__device__ __forceinline__ double bcast0_d(double x){
  int lo = __shfl(__double2loint(x), 0, 64);
  int hi = __shfl(__double2hiint(x), 0, 64);
  return __hiloint2double(hi, lo);
}

__device__ __forceinline__ double wave_sum_d(double d){
  #pragma unroll
  for (int off = 32; off; off >>= 1) d += shfl_down_d(d, off);
  return d; // total valid in lane 0
}

// f32 softmax-key: correctly-rounded expf; for tiny |x| force the exact 1.0f
// that a correctly-rounded exp (numpy/jax) returns.
__device__ __forceinline__ float softmax_key(float x){  // x <= 0
  return (x > -2.9e-8f) ? 1.0f : expf(x);
}

// ---- 0. canary ----
__global__ __launch_bounds__(64) void k_canary(float* __restrict__ outf){
  if (threadIdx.x == 0 && blockIdx.x == 0) outf[0] = 7.0f;
}

// ---- 1. sim_t[c][b] = dot(W_target[target[b]], W_contex[contex[b,c]]) ----
__global__ __launch_bounds__(256) void k_sim(const int* __restrict__ target,
    const int* __restrict__ contex, const float* __restrict__ Wt,
    const float* __restrict__ Wc, float* __restrict__ sim_t){
  int b = blockIdx.x;
  int lane = threadIdx.x & 63, wave = threadIdx.x >> 6;
  int trow = target[b];
  float2 t = *(const float2*)(Wt + (size_t)trow*En + 2*lane);
  for (int c = wave; c < Cn; c += 4){
    int crow = contex[b*Cn + c];
    float2 x = *(const float2*)(Wc + (size_t)crow*En + 2*lane);
    double d = (double)t.x*x.x + (double)t.y*x.y;
    d = wave_sum_d(d);
    if (lane == 0) sim_t[c*Bn + b] = (float)d;
  }
}

// ---- 2. per-column softmax stats over batch axis (legacy dim=0 quirk) ----
__global__ __launch_bounds__(256) void k_colstats(const float* __restrict__ sim_t,
    float* __restrict__ colmax, float* __restrict__ colsum){
  int c = blockIdx.x;
  const float* col = sim_t + (size_t)c*Bn;
  __shared__ float sm[256];
  __shared__ double sd[256];
  int t = threadIdx.x;
  float m = -3.4e38f;
  for (int b = t; b < Bn; b += 256) m = fmaxf(m, col[b]);
  sm[t] = m; __syncthreads();
  for (int s = 128; s; s >>= 1){ if (t < s) sm[t] = fmaxf(sm[t], sm[t+s]); __syncthreads(); }
  float M_ = sm[0];
  double su = 0.0;
  for (int b = t; b < Bn; b += 256) su += exp((double)(col[b] - M_));
  sd[t] = su; __syncthreads();
  for (int s = 128; s; s >>= 1){ if (t < s) sd[t] += sd[t+s]; __syncthreads(); }
  if (t == 0){ colmax[c] = M_; colsum[c] = (float)sd[0]; }
}

// ---- 3. attended rows + per-row cosine with t0 ----
__global__ __launch_bounds__(128) void k_attend(const int* __restrict__ target,
    const int* __restrict__ contex, const float* __restrict__ Wt,
    const float* __restrict__ Wc, const float* __restrict__ sim_t,
    const float* __restrict__ colmax, const float* __restrict__ colsum,
    float* __restrict__ att2, float* __restrict__ cos_b){
  int b = blockIdx.x, t = threadIdx.x;
  __shared__ float score[Cn];
  __shared__ int crow[Cn];
  __shared__ float r0[128], r1[128], r2[128];
  if (t < Cn){
    score[t] = expf(sim_t[t*Bn + b] - colmax[t]) / colsum[t] / DKf;
    crow[t] = contex[b*Cn + t];
  }
  __syncthreads();
  float acc = 0.0f;
  for (int c = 0; c < Cn; c++) acc += score[c] * Wc[(size_t)crow[c]*En + t];
  att2[(size_t)b*En + t] = acc;
  float t0 = Wt[(size_t)target[0]*En + t];
  r0[t] = acc*t0; r1[t] = acc*acc; r2[t] = t0*t0;
  __syncthreads();
  for (int s = 64; s; s >>= 1){
    if (t < s){ r0[t] += r0[t+s]; r1[t] += r1[t+s]; r2[t] += r2[t+s]; }
    __syncthreads();
  }
  if (t == 0)
    cos_b[b] = r0[0] / (fmaxf(sqrtf(r1[0]), 1e-8f) * fmaxf(sqrtf(r2[0]), 1e-8f));
}

// ---- 4. deterministic two-stage column mean of att2 (f64) ----
__global__ __launch_bounds__(128) void k_protosum(const float* __restrict__ att2,
    double* __restrict__ pp){
  int e = threadIdx.x;
  int b0 = blockIdx.x * 64;
  double s = 0.0;
  for (int b = b0; b < b0 + 64; b++) s += (double)att2[(size_t)b*En + e];
  pp[(size_t)blockIdx.x*En + e] = s;
}

__global__ __launch_bounds__(128) void k_protofin(const double* __restrict__ pp,
    double* __restrict__ proto64, float* __restrict__ proto32){
  int e = threadIdx.x;
  double s = 0.0;
  for (int g = 0; g < NB_PS; g++) s += pp[(size_t)g*En + e];
  double v = s / 4096.0;
  proto64[e] = v; proto32[e] = (float)v;
}

// ---- 5. sims vs memory (f64 dot -> f32), block max + exp partial sums ----
__global__ __launch_bounds__(256) void k_simm(const float* __restrict__ mem,
    const double* __restrict__ proto64, float* __restrict__ sim_m,
    float* __restrict__ pmax, double2* __restrict__ partials){
  int lane = threadIdx.x & 63, wave = threadIdx.x >> 6;
  int gw = blockIdx.x*4 + wave, nw = NB_SIMM*4;
  double pa = proto64[2*lane], pb = proto64[2*lane + 1];
  double sp = 0.0, sn = 0.0;
  float wmax = -3.4e38f;
  for (int m = gw; m < Mn; m += nw){
    const float2 x = *(const float2*)(mem + (size_t)m*En + 2*lane);
    double d = (double)x.x*pa + (double)x.y*pb;
    d = wave_sum_d(d);
    if (lane == 0){
      float f = (float)d;
      sim_m[m] = f;
      wmax = fmaxf(wmax, f);
      sp += exp((double)f); sn += exp(-(double)f / DKd);
    }
  }
  __shared__ double s0[4], s1[4];
  __shared__ float s2[4];
  if (lane == 0){ s0[wave] = sp; s1[wave] = sn; s2[wave] = wmax; }
  __syncthreads();
  if (threadIdx.x == 0){
    partials[blockIdx.x] = make_double2(s0[0]+s0[1]+s0[2]+s0[3], s1[0]+s1[1]+s1[2]+s1[3]);
    pmax[blockIdx.x] = fmaxf(fmaxf(s2[0], s2[1]), fmaxf(s2[2], s2[3]));
  }
}

// ---- 6. reduce exp partial sums + global f32 max ----
__global__ __launch_bounds__(256) void k_stats(const double2* __restrict__ partials,
    const float* __restrict__ pmax, double* __restrict__ stats,
    float* __restrict__ maxv){
  __shared__ double sd0[256], sd1[256];
  __shared__ float sm[256];
  int t = threadIdx.x;
  double a = 0.0, b = 0.0; float m = -3.4e38f;
  for (int i = t; i < NB_SIMM; i += 256){
    double2 p = partials[i]; a += p.x; b += p.y;
    m = fmaxf(m, pmax[i]);
  }
  sd0[t] = a; sd1[t] = b; sm[t] = m; __syncthreads();
  for (int s = 128; s; s >>= 1){
    if (t < s){ sd0[t] += sd0[t+s]; sd1[t] += sd1[t+s]; sm[t] = fmaxf(sm[t], sm[t+s]); }
    __syncthreads();
  }
  if (t == 0){ stats[0] = sd0[0]; stats[1] = sd1[0]; maxv[0] = sm[0]; }
}

// ---- 7. f32 softmax keys: histogram + f64 key-sum partials ----
__global__ __launch_bounds__(256) void k_keyhist(const float* __restrict__ sim_m,
    const float* __restrict__ maxv, unsigned* __restrict__ hist,
    double* __restrict__ partials3){
  float M32 = maxv[0];
  int i0 = blockIdx.x*blockDim.x + threadIdx.x;
  int stride = gridDim.x*blockDim.x;
  double s = 0.0;
  for (int m = i0; m < Mn; m += stride){
    float key = softmax_key(sim_m[m] - M32);
    atomicAdd(&hist[sortkey(key) >> 20], 1u);
    s += (double)key;
  }
  __shared__ double sd[256];
  sd[threadIdx.x] = s; __syncthreads();
  for (int st = 128; st; st >>= 1){
    if (threadIdx.x < st) sd[threadIdx.x] += sd[threadIdx.x+st];
    __syncthreads();
  }
  if (threadIdx.x == 0) partials3[blockIdx.x] = sd[0];
}

// ---- 8. reduce key-sum; find boundary key-bin ----
__global__ __launch_bounds__(256) void k_bound2(const double* __restrict__ partials3,
    const unsigned* __restrict__ hist, double* __restrict__ stats,
    int* __restrict__ selmeta){
  __shared__ double sd[256];
  __shared__ unsigned csum[256];
  int t = threadIdx.x;
  double a = 0.0;
  for (int i = t; i < NB_KH; i += 256) a += partials3[i];
  sd[t] = a; __syncthreads();
  for (int s = 128; s; s >>= 1){ if (t < s) sd[t] += sd[t+s]; __syncthreads(); }
  if (t == 0) stats[2] = sd[0];
  unsigned c = 0;
  int hi = HBINS - 1 - 16*t;
  for (int i = 0; i < 16; i++) c += hist[hi - i];
  csum[t] = c; __syncthreads();
  if (t == 0){
    unsigned cum = 0; int b1 = 0; unsigned above = 0;
    for (int ch = 0; ch < 256; ch++){
      if (cum + csum[ch] >= (unsigned)Fn){
        int hi2 = HBINS - 1 - 16*ch;
        for (int i = 0; i < 16; i++){
          unsigned h = hist[hi2 - i];
          if (cum + h >= (unsigned)Fn){ b1 = hi2 - i; above = cum; break; }
          cum += h;
        }
        break;
      }
      cum += csum[ch];
    }
    selmeta[0] = b1; selmeta[1] = (int)above;
  }
}

// ---- 9. collect winners (bin>b1) and boundary candidates (eqA: m<4096, eqB) ----
__global__ __launch_bounds__(256) void k_collect2(const float* __restrict__ sim_m,
    const float* __restrict__ maxv, const int* __restrict__ selmeta,
    int* __restrict__ sel_idx, float* __restrict__ sel_val,
    unsigned* __restrict__ counters, int* __restrict__ eqA_idx,
    float* __restrict__ eqA_key, int* __restrict__ eqB_idx,
    float* __restrict__ eqB_key){
  int b1 = selmeta[0];
  float M32 = maxv[0];
  int i0 = blockIdx.x*blockDim.x + threadIdx.x;
  int stride = gridDim.x*blockDim.x;
  for (int m = i0; m < Mn; m += stride){
    float key = softmax_key(sim_m[m] - M32);
    int bin = (int)(sortkey(key) >> 20);
    if (bin > b1){
      unsigned s = atomicAdd(&counters[0], 1u);
      if (s < (unsigned)Fn){ sel_idx[s] = m; sel_val[s] = key; }
    } else if (bin == b1){
      if (m < CAPA){
        unsigned s = atomicAdd(&counters[1], 1u);
        if (s < (unsigned)CAPA){ eqA_idx[s] = m; eqA_key[s] = key; }
      } else {
        unsigned s = atomicAdd(&counters[2], 1u);
        if (s < (unsigned)CAPB){ eqB_idx[s] = m; eqB_key[s] = key; }
      }
    }
  }
}

// ---- 10. finalize: stable (key desc, idx asc) fill of remaining slots ----
__global__ __launch_bounds__(256) void k_finalize2(const int* __restrict__ selmeta,
    const unsigned* __restrict__ counters, const int* __restrict__ eqA_idx,
    const float* __restrict__ eqA_key, const int* __restrict__ eqB_idx,
    const float* __restrict__ eqB_key, int* __restrict__ sel_idx,
    float* __restrict__ sel_val, unsigned* __restrict__ pos){
  __shared__ float ckey[CAPA + CAPB];
  __shared__ int   cidx[CAPA + CAPB];
  __shared__ unsigned cnt[NBUCK];
  __shared__ float rmin[256], rmax[256];
  __shared__ int sBb; __shared__ unsigned sP;
  int t = threadIdx.x;
  int above = selmeta[1];
  int need = Fn - above; if (need < 0) need = 0;
  int nA = (int)counters[1]; if (nA > CAPA) nA = CAPA; if (nA < 0) nA = 0;
  int nB = (int)counters[2]; if (nB > CAPB) nB = CAPB; if (nB < 0) nB = 0;
  int n = nA + nB;
  for (int i = t; i < nA; i += 256){ cidx[i] = eqA_idx[i]; ckey[i] = eqA_key[i]; }
  for (int i = t; i < nB; i += 256){ cidx[nA+i] = eqB_idx[i]; ckey[nA+i] = eqB_key[i]; }
  __syncthreads();
  if (need == 0 || n == 0) return;
  float mn = 3.4e38f, mx = -3.4e38f;
  for (int i = t; i < n; i += 256){ mn = fminf(mn, ckey[i]); mx = fmaxf(mx, ckey[i]); }
  rmin[t] = mn; rmax[t] = mx; __syncthreads();
  for (int s = 128; s; s >>= 1){
    if (t < s){ rmin[t] = fminf(rmin[t], rmin[t+s]); rmax[t] = fmaxf(rmax[t], rmax[t+s]); }
    __syncthreads();
  }
  bool allEq = (rmin[0] == rmax[0]);
  __syncthreads();
  if (!allEq && n <= 1024){
    // sparse distinct-key regime: exact O(n^2) rank by (key desc, idx asc)
    for (int i = t; i < n; i += 256){
      float ki = ckey[i]; int mi = cidx[i]; int rank = 0;
      for (int j = 0; j < n; j++){
        float kj = ckey[j];
        if (kj > ki || (kj == ki && cidx[j] < mi)) rank++;
      }
      if (rank < need){ sel_idx[above + rank] = mi; sel_val[above + rank] = ki; }
    }
    return;
  }
  // massive-tie regime: smallest `need` indices among candidates
  for (int i = t; i < NBUCK; i += 256) cnt[i] = 0u;
  __syncthreads();
  for (int i = t; i < n; i += 256) atomicAdd(&cnt[cidx[i] >> 6], 1u);
  __syncthreads();
  if (t == 0){
    unsigned cum = 0; int Bb = NBUCK - 1; unsigned P = 0;
    for (int b = 0; b < NBUCK; b++){
      if (cum + cnt[b] >= (unsigned)need){ Bb = b; P = cum; break; }
      cum += cnt[b];
    }
    sBb = Bb; sP = P;
  }
  __syncthreads();
  int Bb = sBb; unsigned P = sP;
  for (int i = t; i < n; i += 256){
    int b = cidx[i] >> 6;
    bool sel = false;
    if (b < Bb) sel = true;
    else if (b == Bb){
      int r = 0;
      for (int j = 0; j < n; j++)
        if ((cidx[j] >> 6) == Bb && cidx[j] < cidx[i]) r++;
      if (P + (unsigned)r < (unsigned)need) sel = true;
    }
    if (sel){
      unsigned p = atomicAdd(pos, 1u);
      if (p < (unsigned)need){
        sel_idx[above + (int)p] = cidx[i];
        sel_val[above + (int)p] = ckey[i];
      }
    }
  }
}

// ---- 11. weighted sums over memory (recomputed sims) + f32 copy-out ----
__global__ __launch_bounds__(256) void k_memctx(const float* __restrict__ mem,
    const double* __restrict__ proto64, const double* __restrict__ stats,
    double* __restrict__ pp2, float* __restrict__ outf){
  int lane = threadIdx.x & 63, wave = threadIdx.x >> 6;
  int gw = blockIdx.x*4 + wave, nw = NB_MC*4;
  double pa = proto64[2*lane], pb = proto64[2*lane + 1];
  double inv_p = 1.0 / (stats[0] * DKd);
  double inv_n = 1.0 / stats[1];
  double apx = 0, apy = 0, anx = 0, any_ = 0;
  for (int m = gw; m < Mn; m += nw){
    const float2 x = *(const float2*)(mem + (size_t)m*En + 2*lane);
    double d = (double)x.x*pa + (double)x.y*pb;
    d = wave_sum_d(d);
    double wp = 0.0, wn = 0.0;
    if (lane == 0){
      float f = (float)d;
      wp = exp((double)f) * inv_p;
      wn = exp(-(double)f / DKd) * inv_n;
    }
    wp = bcast0_d(wp); wn = bcast0_d(wn);
    apx += wp*(double)x.x; apy += wp*(double)x.y;
    anx += wn*(double)x.x; any_ += wn*(double)x.y;
    size_t base = 1 + (size_t)m*En + 2*lane;
    outf[base]     = x.x;
    outf[base + 1] = x.y;
  }
  __shared__ double l0[256], l1[256], l2[256], l3[256];
  l0[threadIdx.x] = apx; l1[threadIdx.x] = apy;
  l2[threadIdx.x] = anx; l3[threadIdx.x] = any_;
  __syncthreads();
  if (wave == 0){
    double a = l0[lane]+l0[64+lane]+l0[128+lane]+l0[192+lane];
    double b = l1[lane]+l1[64+lane]+l1[128+lane]+l1[192+lane];
    double c = l2[lane]+l2[64+lane]+l2[128+lane]+l2[192+lane];
    double d = l3[lane]+l3[64+lane]+l3[128+lane]+l3[192+lane];
    size_t base = (size_t)blockIdx.x * 2 * En;
    pp2[base + 2*lane]          = a;
    pp2[base + 2*lane + 1]      = b;
    pp2[base + En + 2*lane]     = c;
    pp2[base + En + 2*lane + 1] = d;
  }
}

// ---- 12. tail: blocks 0..511 update selected rows; block 512 computes loss ----
__global__ __launch_bounds__(128) void k_tail(const int* __restrict__ repe,
    const int* __restrict__ sel_idx, const float* __restrict__ sel_val,
    const double* __restrict__ stats, const float* __restrict__ mem,
    const float* __restrict__ proto32, const double* __restrict__ pp2,
    const float* __restrict__ cos_b, const int* __restrict__ target,
    const float* __restrict__ Wt, float* __restrict__ outf){
  int t = threadIdx.x;
  if (blockIdx.x < Fn){
    if (repe[0] == 0) return;
    int m = sel_idx[blockIdx.x];
    if ((unsigned)m >= (unsigned)Mn) return;
    // f32-faithful top_val: (key / S32) / DK, matching the reference's divides
    float S32 = (float)stats[2];
    float val = (sel_val[blockIdx.x] / S32) / DKf;
    float s = mem[(size_t)m*En + t] + val * proto32[t];
    __shared__ float r[128];
    r[t] = s*s; __syncthreads();
    for (int st = 64; st; st >>= 1){ if (t < st) r[t] += r[t+st]; __syncthreads(); }
    float nrm = fmaxf(sqrtf(r[0]), 1e-12f);
    outf[1 + (size_t)m*En + t] = s / nrm;
    return;
  }
  // ---- loss block ----
  __shared__ double d0[128], d1[128], d2[128];
  double cs = 0.0;
  for (int b = t; b < Bn; b += 128) cs += (double)cos_b[b];
  d0[t] = cs; __syncthreads();
  for (int s = 64; s; s >>= 1){ if (t < s) d0[t] += d0[t+s]; __syncthreads(); }
  double sum_cos = d0[0]; __syncthreads();

  double t0 = (double)Wt[(size_t)target[0]*En + t];

  double x = (double)proto32[t];
  d0[t] = x*t0; d1[t] = x*x; d2[t] = t0*t0; __syncthreads();
  for (int s = 64; s; s >>= 1){
    if (t < s){ d0[t] += d0[t+s]; d1[t] += d1[t+s]; d2[t] += d2[t+s]; }
    __syncthreads();
  }
  double cos_p = d0[0] / (fmax(sqrt(d1[0]), 1e-8) * fmax(sqrt(d2[0]), 1e-8));
  __syncthreads();

  double mp = 0.0, mn_ = 0.0;
  for (int b = 0; b < NB_MC; b++){
    mp  += pp2[(size_t)b*2*En + t];
    mn_ += pp2[(size_t)b*2*En + En + t];
  }
  d0[t] = mp*t0; d1[t] = mp*mp; d2[t] = t0*t0; __syncthreads();
  for (int s = 64; s; s >>= 1){
    if (t < s){ d0[t] += d0[t+s]; d1[t] += d1[t+s]; d2[t] += d2[t+s]; }
    __syncthreads();
  }
  double cos_m = d0[0] / (fmax(sqrt(d1[0]), 1e-8) * fmax(sqrt(d2[0]), 1e-8));
  __syncthreads();

  d0[t] = mn_*t0; d1[t] = mn_*mn_; d2[t] = t0*t0; __syncthreads();
  for (int s = 64; s; s >>= 1){
    if (t < s){ d0[t] += d0[t+s]; d1[t] += d1[t+s]; d2[t] += d2[t+s]; }
    __syncthreads();
  }
  double cos_n = d0[0] / (fmax(sqrt(d1[0]), 1e-8) * fmax(sqrt(d2[0]), 1e-8));

  if (t == 0){
    double conte = (sum_cos + cos_p + cos_m) / 4098.0;
    double loss = log_sig(conte) + log_sig(-cos_n);
    outf[0] = (float)(-loss);
  }
}

extern "C" void kernel_launch(void* const* d_in, const int* in_sizes, int n_in,
                              void* d_out, int out_size, void* d_ws, size_t ws_size,
                              hipStream_t stream){
  const int*   target = (const int*)d_in[0];
  const int*   contex = (const int*)d_in[1];
  const float* Wt     = (const float*)d_in[2];
  const float* Wc     = (const float*)d_in[3];
  const float* mem    = (const float*)d_in[4];
  const int*   repe   = (const int*)d_in[5];
  float*       outf   = (float*)d_out;   // f32: [ -loss, updated_memory ]

  char* w = (char*)d_ws;
  size_t o = 0;
  auto alloc = [&](size_t sz){ size_t r = o; o = (o + sz + 255) & ~(size_t)255; return r; };

  // --- zeroed region (contiguous, first) ---
  unsigned* hist     = (unsigned*)(w + alloc(HBINS*sizeof(unsigned)));
  unsigned* counters = (unsigned*)(w + alloc(4*sizeof(unsigned)));
  int*      sel_idx  = (int*)     (w + alloc(Fn*sizeof(int)));
  float*    sel_val  = (float*)   (w + alloc(Fn*sizeof(float)));
  size_t zero_bytes = o;
  // --- rest ---
  int*     selmeta  = (int*)    (w + alloc(2*sizeof(int)));
  double*  stats    = (double*) (w + alloc(4*sizeof(double)));
  float*   maxv     = (float*)  (w + alloc(4*sizeof(float)));
  float*   colmax   = (float*)  (w + alloc(Cn*sizeof(float)));
  float*   colsum   = (float*)  (w + alloc(Cn*sizeof(float)));
  double*  proto64  = (double*) (w + alloc(En*sizeof(double)));
  float*   proto32  = (float*)  (w + alloc(En*sizeof(float)));
  double*  pp       = (double*) (w + alloc((size_t)NB_PS*En*sizeof(double)));
  double*  pp2      = (double*) (w + alloc((size_t)NB_MC*2*En*sizeof(double)));
  int*     eqA_idx  = (int*)    (w + alloc(CAPA*sizeof(int)));
  float*   eqA_key  = (float*)  (w + alloc(CAPA*sizeof(float)));
  int*     eqB_idx  = (int*)    (w + alloc(CAPB*sizeof(int)));
  float*   eqB_key  = (float*)  (w + alloc(CAPB*sizeof(float)));
  double2* partials = (double2*)(w + alloc(NB_SIMM*sizeof(double2)));
  float*   pmax     = (float*)  (w + alloc(NB_SIMM*sizeof(float)));
  double*  partials3= (double*) (w + alloc(NB_KH*sizeof(double)));
  float*   cos_b    = (float*)  (w + alloc(Bn*sizeof(float)));
  float*   sim_t    = (float*)  (w + alloc((size_t)Cn*Bn*sizeof(float)));
  float*   att2     = (float*)  (w + alloc((size_t)Bn*En*sizeof(float)));
  float*   sim_m    = (float*)  (w + alloc((size_t)Mn*sizeof(float)));
  (void)in_sizes; (void)n_in; (void)out_size; (void)ws_size;

  int bad = -1; int code = 0;
  auto chk = [&](int idx){
    hipError_t le = hipGetLastError();
    if (le != hipSuccess && bad < 0){ bad = idx; code = (int)le; }
  };

  hipMemsetAsync(d_ws, 0, zero_bytes, stream);                                    chk(0);
  k_canary   <<<1, 64, 0, stream>>>(outf);                                        chk(1);
  k_sim      <<<Bn, 256, 0, stream>>>(target, contex, Wt, Wc, sim_t);             chk(2);
  k_colstats <<<Cn, 256, 0, stream>>>(sim_t, colmax, colsum);                     chk(3);
  k_attend   <<<Bn, 128, 0, stream>>>(target, contex, Wt, Wc, sim_t, colmax, colsum, att2, cos_b); chk(4);
  k_protosum <<<NB_PS, 128, 0, stream>>>(att2, pp);                               chk(5);
  k_protofin <<<1, 128, 0, stream>>>(pp, proto64, proto32);                       chk(6);
  k_simm     <<<NB_SIMM, 256, 0, stream>>>(mem, proto64, sim_m, pmax, partials);  chk(7);
  k_stats    <<<1, 256, 0, stream>>>(partials, pmax, stats, maxv);                chk(8);
  k_keyhist  <<<NB_KH, 256, 0, stream>>>(sim_m, maxv, hist, partials3);           chk(9);
  k_bound2   <<<1, 256, 0, stream>>>(partials3, hist, stats, selmeta);            chk(10);
  k_collect2 <<<512, 256, 0, stream>>>(sim_m, maxv, selmeta, sel_idx, sel_val, counters, eqA_idx, eqA_key, eqB_idx, eqB_key); chk(11);
  k_finalize2<<<1, 256, 0, stream>>>(selmeta, counters, eqA_idx, eqA_key, eqB_idx, eqB_key, sel_idx, sel_val, &counters[3]); chk(12);
  k_memctx   <<<NB_MC, 256, 0, stream>>>(mem, proto64, stats, pp2, outf);         chk(13);
  k_tail     <<<Fn + 1, 128, 0, stream>>>(repe, sel_idx, sel_val, stats, mem, proto32, pp2, cos_b, target, Wt, outf); chk(14);

  if (bad >= 0){
    static float err_payload;
    err_payload = 10000.0f + 100.0f*(float)bad + (float)code;
    hipMemcpyAsync(d_out, &err_payload, sizeof(float), hipMemcpyHostToDevice, stream);
  }
}

// Round 5
// 613.939 us; speedup vs baseline: 4.6945x; 4.6945x over previous
//
#include <hip/hip_runtime.h>
#include <math.h>

#define Bn 4096
#define Cn 50
#define En 128
#define Mn 200000
#define Fn 512
#define CAPA 4096
#define CAPB 2048
#define NBUCK 3136       // ceil(200000/64) = 3125, padded
#define NB_SIMM 784
#define NB_MC 512
#define NB_PS 64
#define NB_KH 256
#define HBINS 4096
#define DKd 11.313708498984761
#define DKf 11.313708498984761f

__device__ __forceinline__ unsigned sortkey(float f){
  unsigned u = __float_as_uint(f);
  return (u & 0x80000000u) ? ~u : (u | 0x80000000u);
}

__device__ __forceinline__ double log_sig(double x){
  return (x >= 0.0) ? -log1p(exp(-x)) : (x - log1p(exp(x)));
}

__device__ __forceinline__ double shfl_down_d(double x, int off){
  int lo = __shfl_down(__double2loint(x), off, 64);
  int hi = __shfl_down(__double2hiint(x), off, 64);
  return __hiloint2double(hi, lo);
}

__device__ __forceinline__ double bcast0_d(double x){
  int lo = __shfl(__double2loint(x), 0, 64);
  int hi = __shfl(__double2hiint(x), 0, 64);
  return __hiloint2double(hi, lo);
}

__device__ __forceinline__ double wave_sum_d(double d){
  #pragma unroll
  for (int off = 32; off; off >>= 1) d += shfl_down_d(d, off);
  return d; // total valid in lane 0
}

// f32 softmax-key: correctly-rounded expf; for tiny |x| force the exact 1.0f
// that a correctly-rounded exp (numpy/jax) returns.
__device__ __forceinline__ float softmax_key(float x){  // x <= 0
  return (x > -2.9e-8f) ? 1.0f : expf(x);
}

// wave-aggregated counter allocation: one atomic per wave instead of per lane.
// Returns this lane's slot (valid only when sel).
__device__ __forceinline__ unsigned wave_alloc(unsigned* ctr, bool sel){
  unsigned long long mask = __ballot(sel);
  if (mask == 0ull) return 0u;
  int lane = threadIdx.x & 63;
  unsigned long long lt = (lane == 0) ? 0ull : (~0ull >> (64 - lane));
  int prefix = __popcll(mask & lt);
  int leader = __ffsll((long long)mask) - 1;
  unsigned base = 0u;
  if (sel && prefix == 0)
    base = atomicAdd(ctr, (unsigned)__popcll(mask));
  base = __shfl(base, leader, 64);
  return base + (unsigned)prefix;
}

// ---- 0. canary ----
__global__ __launch_bounds__(64) void k_canary(float* __restrict__ outf){
  if (threadIdx.x == 0 && blockIdx.x == 0) outf[0] = 7.0f;
}

// ---- 1. sim_t[c][b] = dot(W_target[target[b]], W_contex[contex[b,c]]) ----
__global__ __launch_bounds__(256) void k_sim(const int* __restrict__ target,
    const int* __restrict__ contex, const float* __restrict__ Wt,
    const float* __restrict__ Wc, float* __restrict__ sim_t){
  int b = blockIdx.x;
  int lane = threadIdx.x & 63, wave = threadIdx.x >> 6;
  int trow = target[b];
  float2 t = *(const float2*)(Wt + (size_t)trow*En + 2*lane);
  for (int c = wave; c < Cn; c += 4){
    int crow = contex[b*Cn + c];
    float2 x = *(const float2*)(Wc + (size_t)crow*En + 2*lane);
    double d = (double)t.x*x.x + (double)t.y*x.y;
    d = wave_sum_d(d);
    if (lane == 0) sim_t[c*Bn + b] = (float)d;
  }
}

// ---- 2. per-column softmax stats over batch axis (legacy dim=0 quirk) ----
__global__ __launch_bounds__(256) void k_colstats(const float* __restrict__ sim_t,
    float* __restrict__ colmax, float* __restrict__ colsum){
  int c = blockIdx.x;
  const float* col = sim_t + (size_t)c*Bn;
  __shared__ float sm[256];
  __shared__ double sd[256];
  int t = threadIdx.x;
  float m = -3.4e38f;
  for (int b = t; b < Bn; b += 256) m = fmaxf(m, col[b]);
  sm[t] = m; __syncthreads();
  for (int s = 128; s; s >>= 1){ if (t < s) sm[t] = fmaxf(sm[t], sm[t+s]); __syncthreads(); }
  float M_ = sm[0];
  double su = 0.0;
  for (int b = t; b < Bn; b += 256) su += exp((double)(col[b] - M_));
  sd[t] = su; __syncthreads();
  for (int s = 128; s; s >>= 1){ if (t < s) sd[t] += sd[t+s]; __syncthreads(); }
  if (t == 0){ colmax[c] = M_; colsum[c] = (float)sd[0]; }
}

// ---- 3. attended rows + per-row cosine with t0 ----
__global__ __launch_bounds__(128) void k_attend(const int* __restrict__ target,
    const int* __restrict__ contex, const float* __restrict__ Wt,
    const float* __restrict__ Wc, const float* __restrict__ sim_t,
    const float* __restrict__ colmax, const float* __restrict__ colsum,
    float* __restrict__ att2, float* __restrict__ cos_b){
  int b = blockIdx.x, t = threadIdx.x;
  __shared__ float score[Cn];
  __shared__ int crow[Cn];
  __shared__ float r0[128], r1[128], r2[128];
  if (t < Cn){
    score[t] = expf(sim_t[t*Bn + b] - colmax[t]) / colsum[t] / DKf;
    crow[t] = contex[b*Cn + t];
  }
  __syncthreads();
  float acc = 0.0f;
  for (int c = 0; c < Cn; c++) acc += score[c] * Wc[(size_t)crow[c]*En + t];
  att2[(size_t)b*En + t] = acc;
  float t0 = Wt[(size_t)target[0]*En + t];
  r0[t] = acc*t0; r1[t] = acc*acc; r2[t] = t0*t0;
  __syncthreads();
  for (int s = 64; s; s >>= 1){
    if (t < s){ r0[t] += r0[t+s]; r1[t] += r1[t+s]; r2[t] += r2[t+s]; }
    __syncthreads();
  }
  if (t == 0)
    cos_b[b] = r0[0] / (fmaxf(sqrtf(r1[0]), 1e-8f) * fmaxf(sqrtf(r2[0]), 1e-8f));
}

// ---- 4. deterministic two-stage column mean of att2 (f64) ----
__global__ __launch_bounds__(128) void k_protosum(const float* __restrict__ att2,
    double* __restrict__ pp){
  int e = threadIdx.x;
  int b0 = blockIdx.x * 64;
  double s = 0.0;
  for (int b = b0; b < b0 + 64; b++) s += (double)att2[(size_t)b*En + e];
  pp[(size_t)blockIdx.x*En + e] = s;
}

__global__ __launch_bounds__(128) void k_protofin(const double* __restrict__ pp,
    double* __restrict__ proto64, float* __restrict__ proto32){
  int e = threadIdx.x;
  double s = 0.0;
  for (int g = 0; g < NB_PS; g++) s += pp[(size_t)g*En + e];
  double v = s / 4096.0;
  proto64[e] = v; proto32[e] = (float)v;
}

// ---- 5. sims vs memory (f64 dot -> f32), block max + exp partial sums ----
__global__ __launch_bounds__(256) void k_simm(const float* __restrict__ mem,
    const double* __restrict__ proto64, float* __restrict__ sim_m,
    float* __restrict__ pmax, double2* __restrict__ partials){
  int lane = threadIdx.x & 63, wave = threadIdx.x >> 6;
  int gw = blockIdx.x*4 + wave, nw = NB_SIMM*4;
  double pa = proto64[2*lane], pb = proto64[2*lane + 1];
  double sp = 0.0, sn = 0.0;
  float wmax = -3.4e38f;
  for (int m = gw; m < Mn; m += nw){
    const float2 x = *(const float2*)(mem + (size_t)m*En + 2*lane);
    double d = (double)x.x*pa + (double)x.y*pb;
    d = wave_sum_d(d);
    if (lane == 0){
      float f = (float)d;
      sim_m[m] = f;
      wmax = fmaxf(wmax, f);
      sp += exp((double)f); sn += exp(-(double)f / DKd);
    }
  }
  __shared__ double s0[4], s1[4];
  __shared__ float s2[4];
  if (lane == 0){ s0[wave] = sp; s1[wave] = sn; s2[wave] = wmax; }
  __syncthreads();
  if (threadIdx.x == 0){
    partials[blockIdx.x] = make_double2(s0[0]+s0[1]+s0[2]+s0[3], s1[0]+s1[1]+s1[2]+s1[3]);
    pmax[blockIdx.x] = fmaxf(fmaxf(s2[0], s2[1]), fmaxf(s2[2], s2[3]));
  }
}

// ---- 6. reduce exp partial sums + global f32 max ----
__global__ __launch_bounds__(256) void k_stats(const double2* __restrict__ partials,
    const float* __restrict__ pmax, double* __restrict__ stats,
    float* __restrict__ maxv){
  __shared__ double sd0[256], sd1[256];
  __shared__ float sm[256];
  int t = threadIdx.x;
  double a = 0.0, b = 0.0; float m = -3.4e38f;
  for (int i = t; i < NB_SIMM; i += 256){
    double2 p = partials[i]; a += p.x; b += p.y;
    m = fmaxf(m, pmax[i]);
  }
  sd0[t] = a; sd1[t] = b; sm[t] = m; __syncthreads();
  for (int s = 128; s; s >>= 1){
    if (t < s){ sd0[t] += sd0[t+s]; sd1[t] += sd1[t+s]; sm[t] = fmaxf(sm[t], sm[t+s]); }
    __syncthreads();
  }
  if (t == 0){ stats[0] = sd0[0]; stats[1] = sd1[0]; maxv[0] = sm[0]; }
}

// ---- 7. f32 softmax keys: LDS histogram + f64 key-sum partials ----
__global__ __launch_bounds__(256) void k_keyhist(const float* __restrict__ sim_m,
    const float* __restrict__ maxv, unsigned* __restrict__ hist,
    double* __restrict__ partials3){
  __shared__ unsigned lh[HBINS];
  for (int i = threadIdx.x; i < HBINS; i += 256) lh[i] = 0u;
  __syncthreads();
  float M32 = maxv[0];
  int i0 = blockIdx.x*blockDim.x + threadIdx.x;
  int stride = gridDim.x*blockDim.x;
  double s = 0.0;
  for (int m = i0; m < Mn; m += stride){
    float key = softmax_key(sim_m[m] - M32);
    atomicAdd(&lh[sortkey(key) >> 20], 1u);
    s += (double)key;
  }
  __syncthreads();
  // flush only non-zero bins (typically 1-3 per block)
  for (int i = threadIdx.x; i < HBINS; i += 256){
    unsigned v = lh[i];
    if (v) atomicAdd(&hist[i], v);
  }
  __shared__ double sd[256];
  sd[threadIdx.x] = s; __syncthreads();
  for (int st = 128; st; st >>= 1){
    if (threadIdx.x < st) sd[threadIdx.x] += sd[threadIdx.x+st];
    __syncthreads();
  }
  if (threadIdx.x == 0) partials3[blockIdx.x] = sd[0];
}

// ---- 8. reduce key-sum; find boundary key-bin ----
__global__ __launch_bounds__(256) void k_bound2(const double* __restrict__ partials3,
    const unsigned* __restrict__ hist, double* __restrict__ stats,
    int* __restrict__ selmeta){
  __shared__ double sd[256];
  __shared__ unsigned csum[256];
  int t = threadIdx.x;
  double a = 0.0;
  for (int i = t; i < NB_KH; i += 256) a += partials3[i];
  sd[t] = a; __syncthreads();
  for (int s = 128; s; s >>= 1){ if (t < s) sd[t] += sd[t+s]; __syncthreads(); }
  if (t == 0) stats[2] = sd[0];
  unsigned c = 0;
  int hi = HBINS - 1 - 16*t;
  for (int i = 0; i < 16; i++) c += hist[hi - i];
  csum[t] = c; __syncthreads();
  if (t == 0){
    unsigned cum = 0; int b1 = 0; unsigned above = 0;
    for (int ch = 0; ch < 256; ch++){
      if (cum + csum[ch] >= (unsigned)Fn){
        int hi2 = HBINS - 1 - 16*ch;
        for (int i = 0; i < 16; i++){
          unsigned h = hist[hi2 - i];
          if (cum + h >= (unsigned)Fn){ b1 = hi2 - i; above = cum; break; }
          cum += h;
        }
        break;
      }
      cum += csum[ch];
    }
    selmeta[0] = b1; selmeta[1] = (int)above;
  }
}

// ---- 9. collect winners (bin>b1) and boundary candidates (eqA: m<4096, eqB) ----
//         wave-aggregated counter atomics (64x fewer same-address atomics)
__global__ __launch_bounds__(256) void k_collect2(const float* __restrict__ sim_m,
    const float* __restrict__ maxv, const int* __restrict__ selmeta,
    int* __restrict__ sel_idx, float* __restrict__ sel_val,
    unsigned* __restrict__ counters, int* __restrict__ eqA_idx,
    float* __restrict__ eqA_key, int* __restrict__ eqB_idx,
    float* __restrict__ eqB_key){
  int b1 = selmeta[0];
  float M32 = maxv[0];
  int i0 = blockIdx.x*blockDim.x + threadIdx.x;
  int stride = gridDim.x*blockDim.x;
  for (int m = i0; m < Mn; m += stride){
    float key = softmax_key(sim_m[m] - M32);
    int bin = (int)(sortkey(key) >> 20);
    bool w0 = (bin > b1);
    bool w1 = (bin == b1) && (m < CAPA);
    bool w2 = (bin == b1) && (m >= CAPA);
    unsigned p0 = wave_alloc(&counters[0], w0);
    unsigned p1 = wave_alloc(&counters[1], w1);
    unsigned p2 = wave_alloc(&counters[2], w2);
    if (w0 && p0 < (unsigned)Fn){ sel_idx[p0] = m; sel_val[p0] = key; }
    if (w1 && p1 < (unsigned)CAPA){ eqA_idx[p1] = m; eqA_key[p1] = key; }
    if (w2 && p2 < (unsigned)CAPB){ eqB_idx[p2] = m; eqB_key[p2] = key; }
  }
}

// ---- 10. finalize: stable (key desc, idx asc) fill of remaining slots ----
__global__ __launch_bounds__(256) void k_finalize2(const int* __restrict__ selmeta,
    const unsigned* __restrict__ counters, const int* __restrict__ eqA_idx,
    const float* __restrict__ eqA_key, const int* __restrict__ eqB_idx,
    const float* __restrict__ eqB_key, int* __restrict__ sel_idx,
    float* __restrict__ sel_val, unsigned* __restrict__ pos){
  __shared__ float ckey[CAPA + CAPB];
  __shared__ int   cidx[CAPA + CAPB];
  __shared__ unsigned cnt[NBUCK];
  __shared__ float rmin[256], rmax[256];
  __shared__ int sBb; __shared__ unsigned sP;
  int t = threadIdx.x;
  int above = selmeta[1];
  int need = Fn - above; if (need < 0) need = 0;
  int nA = (int)counters[1]; if (nA > CAPA) nA = CAPA; if (nA < 0) nA = 0;
  int nB = (int)counters[2]; if (nB > CAPB) nB = CAPB; if (nB < 0) nB = 0;
  int n = nA + nB;
  for (int i = t; i < nA; i += 256){ cidx[i] = eqA_idx[i]; ckey[i] = eqA_key[i]; }
  for (int i = t; i < nB; i += 256){ cidx[nA+i] = eqB_idx[i]; ckey[nA+i] = eqB_key[i]; }
  __syncthreads();
  if (need == 0 || n == 0) return;
  float mn = 3.4e38f, mx = -3.4e38f;
  for (int i = t; i < n; i += 256){ mn = fminf(mn, ckey[i]); mx = fmaxf(mx, ckey[i]); }
  rmin[t] = mn; rmax[t] = mx; __syncthreads();
  for (int s = 128; s; s >>= 1){
    if (t < s){ rmin[t] = fminf(rmin[t], rmin[t+s]); rmax[t] = fmaxf(rmax[t], rmax[t+s]); }
    __syncthreads();
  }
  bool allEq = (rmin[0] == rmax[0]);
  __syncthreads();
  if (!allEq && n <= 1024){
    // sparse distinct-key regime: exact O(n^2) rank by (key desc, idx asc)
    for (int i = t; i < n; i += 256){
      float ki = ckey[i]; int mi = cidx[i]; int rank = 0;
      for (int j = 0; j < n; j++){
        float kj = ckey[j];
        if (kj > ki || (kj == ki && cidx[j] < mi)) rank++;
      }
      if (rank < need){ sel_idx[above + rank] = mi; sel_val[above + rank] = ki; }
    }
    return;
  }
  // massive-tie regime: smallest `need` indices among candidates
  for (int i = t; i < NBUCK; i += 256) cnt[i] = 0u;
  __syncthreads();
  for (int i = t; i < n; i += 256) atomicAdd(&cnt[cidx[i] >> 6], 1u);
  __syncthreads();
  if (t == 0){
    unsigned cum = 0; int Bb = NBUCK - 1; unsigned P = 0;
    for (int b = 0; b < NBUCK; b++){
      if (cum + cnt[b] >= (unsigned)need){ Bb = b; P = cum; break; }
      cum += cnt[b];
    }
    sBb = Bb; sP = P;
  }
  __syncthreads();
  int Bb = sBb; unsigned P = sP;
  for (int i = t; i < n; i += 256){
    int b = cidx[i] >> 6;
    bool sel = false;
    if (b < Bb) sel = true;
    else if (b == Bb){
      int r = 0;
      for (int j = 0; j < n; j++)
        if ((cidx[j] >> 6) == Bb && cidx[j] < cidx[i]) r++;
      if (P + (unsigned)r < (unsigned)need) sel = true;
    }
    if (sel){
      unsigned p = atomicAdd(pos, 1u);
      if (p < (unsigned)need){
        sel_idx[above + (int)p] = cidx[i];
        sel_val[above + (int)p] = ckey[i];
      }
    }
  }
}

// ---- 11. weighted sums over memory (recomputed sims) + f32 copy-out ----
__global__ __launch_bounds__(256) void k_memctx(const float* __restrict__ mem,
    const double* __restrict__ proto64, const double* __restrict__ stats,
    double* __restrict__ pp2, float* __restrict__ outf){
  int lane = threadIdx.x & 63, wave = threadIdx.x >> 6;
  int gw = blockIdx.x*4 + wave, nw = NB_MC*4;
  double pa = proto64[2*lane], pb = proto64[2*lane + 1];
  double inv_p = 1.0 / (stats[0] * DKd);
  double inv_n = 1.0 / stats[1];
  double apx = 0, apy = 0, anx = 0, any_ = 0;
  for (int m = gw; m < Mn; m += nw){
    const float2 x = *(const float2*)(mem + (size_t)m*En + 2*lane);
    double d = (double)x.x*pa + (double)x.y*pb;
    d = wave_sum_d(d);
    double wp = 0.0, wn = 0.0;
    if (lane == 0){
      float f = (float)d;
      wp = exp((double)f) * inv_p;
      wn = exp(-(double)f / DKd) * inv_n;
    }
    wp = bcast0_d(wp); wn = bcast0_d(wn);
    apx += wp*(double)x.x; apy += wp*(double)x.y;
    anx += wn*(double)x.x; any_ += wn*(double)x.y;
    size_t base = 1 + (size_t)m*En + 2*lane;
    outf[base]     = x.x;
    outf[base + 1] = x.y;
  }
  __shared__ double l0[256], l1[256], l2[256], l3[256];
  l0[threadIdx.x] = apx; l1[threadIdx.x] = apy;
  l2[threadIdx.x] = anx; l3[threadIdx.x] = any_;
  __syncthreads();
  if (wave == 0){
    double a = l0[lane]+l0[64+lane]+l0[128+lane]+l0[192+lane];
    double b = l1[lane]+l1[64+lane]+l1[128+lane]+l1[192+lane];
    double c = l2[lane]+l2[64+lane]+l2[128+lane]+l2[192+lane];
    double d = l3[lane]+l3[64+lane]+l3[128+lane]+l3[192+lane];
    size_t base = (size_t)blockIdx.x * 2 * En;
    pp2[base + 2*lane]          = a;
    pp2[base + 2*lane + 1]      = b;
    pp2[base + En + 2*lane]     = c;
    pp2[base + En + 2*lane + 1] = d;
  }
}

// ---- 12. tail: blocks 0..511 update selected rows; block 512 computes loss ----
__global__ __launch_bounds__(128) void k_tail(const int* __restrict__ repe,
    const int* __restrict__ sel_idx, const float* __restrict__ sel_val,
    const double* __restrict__ stats, const float* __restrict__ mem,
    const float* __restrict__ proto32, const double* __restrict__ pp2,
    const float* __restrict__ cos_b, const int* __restrict__ target,
    const float* __restrict__ Wt, float* __restrict__ outf){
  int t = threadIdx.x;
  if (blockIdx.x < Fn){
    if (repe[0] == 0) return;
    int m = sel_idx[blockIdx.x];
    if ((unsigned)m >= (unsigned)Mn) return;
    float S32 = (float)stats[2];
    float val = (sel_val[blockIdx.x] / S32) / DKf;
    float s = mem[(size_t)m*En + t] + val * proto32[t];
    __shared__ float r[128];
    r[t] = s*s; __syncthreads();
    for (int st = 64; st; st >>= 1){ if (t < st) r[t] += r[t+st]; __syncthreads(); }
    float nrm = fmaxf(sqrtf(r[0]), 1e-12f);
    outf[1 + (size_t)m*En + t] = s / nrm;
    return;
  }
  // ---- loss block ----
  __shared__ double d0[128], d1[128], d2[128];
  double cs = 0.0;
  for (int b = t; b < Bn; b += 128) cs += (double)cos_b[b];
  d0[t] = cs; __syncthreads();
  for (int s = 64; s; s >>= 1){ if (t < s) d0[t] += d0[t+s]; __syncthreads(); }
  double sum_cos = d0[0]; __syncthreads();

  double t0 = (double)Wt[(size_t)target[0]*En + t];

  double x = (double)proto32[t];
  d0[t] = x*t0; d1[t] = x*x; d2[t] = t0*t0; __syncthreads();
  for (int s = 64; s; s >>= 1){
    if (t < s){ d0[t] += d0[t+s]; d1[t] += d1[t+s]; d2[t] += d2[t+s]; }
    __syncthreads();
  }
  double cos_p = d0[0] / (fmax(sqrt(d1[0]), 1e-8) * fmax(sqrt(d2[0]), 1e-8));
  __syncthreads();

  double mp = 0.0, mn_ = 0.0;
  for (int b = 0; b < NB_MC; b++){
    mp  += pp2[(size_t)b*2*En + t];
    mn_ += pp2[(size_t)b*2*En + En + t];
  }
  d0[t] = mp*t0; d1[t] = mp*mp; d2[t] = t0*t0; __syncthreads();
  for (int s = 64; s; s >>= 1){
    if (t < s){ d0[t] += d0[t+s]; d1[t] += d1[t+s]; d2[t] += d2[t+s]; }
    __syncthreads();
  }
  double cos_m = d0[0] / (fmax(sqrt(d1[0]), 1e-8) * fmax(sqrt(d2[0]), 1e-8));
  __syncthreads();

  d0[t] = mn_*t0; d1[t] = mn_*mn_; d2[t] = t0*t0; __syncthreads();
  for (int s = 64; s; s >>= 1){
    if (t < s){ d0[t] += d0[t+s]; d1[t] += d1[t+s]; d2[t] += d2[t+s]; }
    __syncthreads();
  }
  double cos_n = d0[0] / (fmax(sqrt(d1[0]), 1e-8) * fmax(sqrt(d2[0]), 1e-8));

  if (t == 0){
    double conte = (sum_cos + cos_p + cos_m) / 4098.0;
    double loss = log_sig(conte) + log_sig(-cos_n);
    outf[0] = (float)(-loss);
  }
}

extern "C" void kernel_launch(void* const* d_in, const int* in_sizes, int n_in,
                              void* d_out, int out_size, void* d_ws, size_t ws_size,
                              hipStream_t stream){
  const int*   target = (const int*)d_in[0];
  const int*   contex = (const int*)d_in[1];
  const float* Wt     = (const float*)d_in[2];
  const float* Wc     = (const float*)d_in[3];
  const float* mem    = (const float*)d_in[4];
  const int*   repe   = (const int*)d_in[5];
  float*       outf   = (float*)d_out;   // f32: [ -loss, updated_memory ]

  char* w = (char*)d_ws;
  size_t o = 0;
  auto alloc = [&](size_t sz){ size_t r = o; o = (o + sz + 255) & ~(size_t)255; return r; };

  // --- zeroed region (contiguous, first) ---
  unsigned* hist     = (unsigned*)(w + alloc(HBINS*sizeof(unsigned)));
  unsigned* counters = (unsigned*)(w + alloc(4*sizeof(unsigned)));
  int*      sel_idx  = (int*)     (w + alloc(Fn*sizeof(int)));
  float*    sel_val  = (float*)   (w + alloc(Fn*sizeof(float)));
  size_t zero_bytes = o;
  // --- rest ---
  int*     selmeta  = (int*)    (w + alloc(2*sizeof(int)));
  double*  stats    = (double*) (w + alloc(4*sizeof(double)));
  float*   maxv     = (float*)  (w + alloc(4*sizeof(float)));
  float*   colmax   = (float*)  (w + alloc(Cn*sizeof(float)));
  float*   colsum   = (float*)  (w + alloc(Cn*sizeof(float)));
  double*  proto64  = (double*) (w + alloc(En*sizeof(double)));
  float*   proto32  = (float*)  (w + alloc(En*sizeof(float)));
  double*  pp       = (double*) (w + alloc((size_t)NB_PS*En*sizeof(double)));
  double*  pp2      = (double*) (w + alloc((size_t)NB_MC*2*En*sizeof(double)));
  int*     eqA_idx  = (int*)    (w + alloc(CAPA*sizeof(int)));
  float*   eqA_key  = (float*)  (w + alloc(CAPA*sizeof(float)));
  int*     eqB_idx  = (int*)    (w + alloc(CAPB*sizeof(int)));
  float*   eqB_key  = (float*)  (w + alloc(CAPB*sizeof(float)));
  double2* partials = (double2*)(w + alloc(NB_SIMM*sizeof(double2)));
  float*   pmax     = (float*)  (w + alloc(NB_SIMM*sizeof(float)));
  double*  partials3= (double*) (w + alloc(NB_KH*sizeof(double)));
  float*   cos_b    = (float*)  (w + alloc(Bn*sizeof(float)));
  float*   sim_t    = (float*)  (w + alloc((size_t)Cn*Bn*sizeof(float)));
  float*   att2     = (float*)  (w + alloc((size_t)Bn*En*sizeof(float)));
  float*   sim_m    = (float*)  (w + alloc((size_t)Mn*sizeof(float)));
  (void)in_sizes; (void)n_in; (void)out_size; (void)ws_size;

  int bad = -1; int code = 0;
  auto chk = [&](int idx){
    hipError_t le = hipGetLastError();
    if (le != hipSuccess && bad < 0){ bad = idx; code = (int)le; }
  };

  hipMemsetAsync(d_ws, 0, zero_bytes, stream);                                    chk(0);
  k_canary   <<<1, 64, 0, stream>>>(outf);                                        chk(1);
  k_sim      <<<Bn, 256, 0, stream>>>(target, contex, Wt, Wc, sim_t);             chk(2);
  k_colstats <<<Cn, 256, 0, stream>>>(sim_t, colmax, colsum);                     chk(3);
  k_attend   <<<Bn, 128, 0, stream>>>(target, contex, Wt, Wc, sim_t, colmax, colsum, att2, cos_b); chk(4);
  k_protosum <<<NB_PS, 128, 0, stream>>>(att2, pp);                               chk(5);
  k_protofin <<<1, 128, 0, stream>>>(pp, proto64, proto32);                       chk(6);
  k_simm     <<<NB_SIMM, 256, 0, stream>>>(mem, proto64, sim_m, pmax, partials);  chk(7);
  k_stats    <<<1, 256, 0, stream>>>(partials, pmax, stats, maxv);                chk(8);
  k_keyhist  <<<NB_KH, 256, 0, stream>>>(sim_m, maxv, hist, partials3);           chk(9);
  k_bound2   <<<1, 256, 0, stream>>>(partials3, hist, stats, selmeta);            chk(10);
  k_collect2 <<<512, 256, 0, stream>>>(sim_m, maxv, selmeta, sel_idx, sel_val, counters, eqA_idx, eqA_key, eqB_idx, eqB_key); chk(11);
  k_finalize2<<<1, 256, 0, stream>>>(selmeta, counters, eqA_idx, eqA_key, eqB_idx, eqB_key, sel_idx, sel_val, &counters[3]); chk(12);
  k_memctx   <<<NB_MC, 256, 0, stream>>>(mem, proto64, stats, pp2, outf);         chk(13);
  k_tail     <<<Fn + 1, 128, 0, stream>>>(repe, sel_idx, sel_val, stats, mem, proto32, pp2, cos_b, target, Wt, outf); chk(14);

  if (bad >= 0){
    static float err_payload;
    err_payload = 10000.0f + 100.0f*(float)bad + (float)code;
    hipMemcpyAsync(d_out, &err_payload, sizeof(float), hipMemcpyHostToDevice, stream);
  }
}